// Round 11
// baseline (174.891 us; speedup 1.0000x reference)
//
#include <hip/hip_runtime.h>

typedef __attribute__((ext_vector_type(8))) short short8;
typedef __attribute__((ext_vector_type(4))) float f32x4;

__device__ __forceinline__ unsigned short f2bf(float f) {
    union { float f; unsigned int i; } v; v.f = f;
    unsigned int x = v.i;
    return (unsigned short)((x + 0x7FFFu + ((x >> 16) & 1u)) >> 16); // RNE, finite inputs
}
__device__ __forceinline__ f32x4 mfma16(short8 a, short8 b, f32x4 c) {
    return __builtin_amdgcn_mfma_f32_16x16x32_bf16(a, b, c, 0, 0, 0);
}

// ---------------------------------------------------------------------------
// K1: coalesced-write input prep (verified in the 164.5 us pipeline).
// ---------------------------------------------------------------------------
__global__ void __launch_bounds__(256, 4)
prep_kernel(const float* __restrict__ x,
            const float* __restrict__ Wq,
            const float* __restrict__ Wk,
            const float* __restrict__ Wv,
            unsigned short* __restrict__ xavg,
            unsigned short* __restrict__ xsum,
            unsigned short* __restrict__ Wb)
{
    const int blk = blockIdx.x;
    const int t = threadIdx.x;
    if (blk >= 512) {                       // weight conversion (unchanged math)
        const int f = (blk - 512) * 512 + t;    // float4 id; pair (f, f+256)
        const int m = f >> 16;                  // 65536 float4 per matrix
        const int o = f & 65535;
        const float4* s4 = (const float4*)((m == 0) ? Wq : (m == 1) ? Wk : Wv);
        float4 a = s4[o];
        float4 b = s4[o + 256];
        ushort4* d4 = (ushort4*)(Wb + (size_t)m * 262144);
        d4[o]       = make_ushort4(f2bf(a.x), f2bf(a.y), f2bf(a.z), f2bf(a.w));
        d4[o + 256] = make_ushort4(f2bf(b.x), f2bf(b.y), f2bf(b.z), f2bf(b.w));
        return;
    }

    const int b    = blk >> 6;              // 0..7
    const int rem  = blk & 63;
    const int cg   = rem >> 1;              // 0..31 : 16-channel group
    const int half = rem & 1;               // 0..1  : h-rows 0..31 / 32..63
    const int c0   = cg * 16;

    __shared__ float part[4][512];          // quad-sums for 4 channels
    __shared__ unsigned short xsT[16][128]; // [c_local][g_local]
    __shared__ unsigned short xaT[16][128]; // [c_local][n_local]

    for (int cg4 = 0; cg4 < 4; ++cg4) {     // 4 phases x 4 channels
        float4 a0, a1, b0, b1, c0v, c1, d0, d1;
        {
            const float* base = x + ((size_t)(b * 512 + c0 + cg4 * 4) * 4096) + half * 2048;
            const float4* p0 = (const float4*)(base);
            const float4* p1 = (const float4*)(base + 4096);
            const float4* p2 = (const float4*)(base + 8192);
            const float4* p3 = (const float4*)(base + 12288);
            a0 = p0[t]; a1 = p0[t + 256];
            b0 = p1[t]; b1 = p1[t + 256];
            c0v = p2[t]; c1 = p2[t + 256];
            d0 = p3[t]; d1 = p3[t + 256];
        }
        part[0][t]       = a0.x + a0.y + a0.z + a0.w;
        part[0][t + 256] = a1.x + a1.y + a1.z + a1.w;
        part[1][t]       = b0.x + b0.y + b0.z + b0.w;
        part[1][t + 256] = b1.x + b1.y + b1.z + b1.w;
        part[2][t]       = c0v.x + c0v.y + c0v.z + c0v.w;
        part[2][t + 256] = c1.x + c1.y + c1.z + c1.w;
        part[3][t]       = d0.x + d0.y + d0.z + d0.w;
        part[3][t + 256] = d1.x + d1.y + d1.z + d1.w;
        __syncthreads();

        if (t < 128) {                      // xsum: group g = 16 consecutive pixels
            const int g = t;
#pragma unroll
            for (int ci = 0; ci < 4; ++ci) {
                float4 q = *(const float4*)&part[ci][4 * g];
                xsT[cg4 * 4 + ci][g] = f2bf(q.x + q.y + q.z + q.w);
            }
        } else {                            // xavg: spatial block n = bh*16+bw (local)
            const int n = t - 128;
            const int bh = n >> 4, bw = n & 15;
#pragma unroll
            for (int ci = 0; ci < 4; ++ci) {
                float m = (part[ci][(bh * 4 + 0) * 16 + bw] + part[ci][(bh * 4 + 1) * 16 + bw] +
                           part[ci][(bh * 4 + 2) * 16 + bw] + part[ci][(bh * 4 + 3) * 16 + bw]) * 0.0625f;
                xaT[cg4 * 4 + ci][n] = f2bf(m);
            }
        }
        __syncthreads();                    // part reused next phase
    }

    {
        const int g = t >> 1, chunk = t & 1;    // row 0..127, 8-channel chunk
        const size_t rowbase = ((size_t)(b * 256) + half * 128 + g) * 512 + c0 + chunk * 8;
        short8 vs, va;
#pragma unroll
        for (int j = 0; j < 8; ++j) {
            vs[j] = (short)xsT[chunk * 8 + j][g];
            va[j] = (short)xaT[chunk * 8 + j][g];
        }
        *(short8*)(xsum + rowbase) = vs;
        *(short8*)(xavg + rowbase) = va;
    }
}

// ---------------------------------------------------------------------------
// K2: joint projection, RE-TILED FOR TLP. 32x16 tile/wave (3 loads -> 2
// MFMAs, ~50 VGPR), grid 1536 blocks, launch_bounds(256,8) -> up to 8
// waves/SIMD (2.7x the previous 3/SIMD). K2's 294 MB of L2 operand reads
// should take ~9 us at the L2 ceiling; at 3 blocks/CU it was L2-LATENCY-
// bound. Per-output K-accumulation order unchanged -> bit-identical.
// Blocks 0..1023:  QK[2048x1024] = xavg @ [Wq;Wk]^T + [bq;bk].
// Blocks 1024..1535: VsT[b][c][m] = (xsum[b] @ Wv^T + 16*bv)^T.
// ---------------------------------------------------------------------------
__global__ void __launch_bounds__(256, 8)
proj_gemm(const unsigned short* __restrict__ xavg,
          const unsigned short* __restrict__ xsum,
          const unsigned short* __restrict__ Wb,
          const float* __restrict__ bq,
          const float* __restrict__ bk,
          const float* __restrict__ bv,
          unsigned short* __restrict__ QK,
          unsigned short* __restrict__ VsT)
{
    const int blk = blockIdx.x;
    const int lane = threadIdx.x & 63, quad = lane >> 4, r16 = lane & 15;
    const int w = threadIdx.x >> 6;

    if (blk < 1024) {                       // ---- QK projection ----
        const int wave = blk * 4 + w;       // 0..4095
        const int mt = wave >> 6;           // 0..63 (32-row tiles)
        const int nt = wave & 63;           // 0..63 (16-col tiles)
        const unsigned short* xp0 = xavg + (size_t)(mt * 32 + r16) * 512 + quad * 8;
        const unsigned short* xp1 = xp0 + 16 * 512;
        const unsigned short* wp0 = Wb + (size_t)(nt * 16 + r16) * 512 + quad * 8;

        f32x4 a00 = {0,0,0,0}, a10 = a00;
#pragma unroll 2
        for (int k = 0; k < 512; k += 32) {
            short8 qa0 = *(const short8*)(xp0 + k);
            short8 qa1 = *(const short8*)(xp1 + k);
            short8 b0 = *(const short8*)(wp0 + k);
            a00 = mfma16(qa0, b0, a00);
            a10 = mfma16(qa1, b0, a10);
        }
        const int row0 = mt * 32 + quad * 4;
        const int c = nt * 16 + r16;
        const float bias = (c < 512) ? bq[c] : bk[c - 512];
#pragma unroll
        for (int r = 0; r < 4; ++r) {
            QK[(size_t)(row0 + r) * 1024 + c]      = f2bf(a00[r] + bias);
            QK[(size_t)(row0 + 16 + r) * 1024 + c] = f2bf(a10[r] + bias);
        }
    } else {                                // ---- V projection (transposed) ----
        const int vblk = blk - 1024;        // 0..511
        const int b = vblk >> 6;            // 0..7
        const int wib = (vblk & 63) * 4 + w;    // 0..255
        const int mt2 = wib >> 5;           // 0..7 (32-row tiles of 256)
        const int nt = wib & 31;            // 0..31 (16-col tiles of 512)
        const unsigned short* xp0 = xsum + (size_t)b * 131072 + (size_t)(mt2 * 32 + r16) * 512 + quad * 8;
        const unsigned short* xp1 = xp0 + 16 * 512;
        const unsigned short* wp0 = Wb + 524288 + (size_t)(nt * 16 + r16) * 512 + quad * 8;

        f32x4 a00 = {0,0,0,0}, a10 = a00;
#pragma unroll 2
        for (int k = 0; k < 512; k += 32) {
            short8 qa0 = *(const short8*)(xp0 + k);
            short8 qa1 = *(const short8*)(xp1 + k);
            short8 b0 = *(const short8*)(wp0 + k);
            a00 = mfma16(qa0, b0, a00);
            a10 = mfma16(qa1, b0, a10);
        }
        unsigned short* vb = VsT + (size_t)b * 131072;
        const int m0 = mt2 * 32 + quad * 4;
        const int c = nt * 16 + r16;
        const float bias = 16.f * bv[c];
#pragma unroll
        for (int r = 0; r < 4; ++r) {
            vb[(size_t)c * 256 + m0 + r]      = f2bf(a00[r] + bias);
            vb[(size_t)c * 256 + m0 + 16 + r] = f2bf(a10[r] + bias);
        }
    }
}

// ---------------------------------------------------------------------------
// K3: scores + softmax + AV + expand, merged (verbatim the 164.5 us champion:
// 256 blocks, 2x score duplication, wave-coalesced 1 KB/instr writes).
// ---------------------------------------------------------------------------
__global__ void __launch_bounds__(256, 2)
score_av(const unsigned short* __restrict__ QK,
         const unsigned short* __restrict__ VsT,
         float* __restrict__ out)
{
    __shared__ union {
        float S[16][257];
        float osT[256][17];
    } u;
    __shared__ __align__(16) unsigned short Abf[16][264];   // +8 pad: row stride 528 B

    const int b = blockIdx.y;
    const int strip = blockIdx.x >> 1;      // 0..15
    const int chalf = blockIdx.x & 1;       // 0..1: which 256-channel half
    const int w = threadIdx.x >> 6, lane = threadIdx.x & 63;
    const int quad = lane >> 4, r16 = lane & 15;

    // ---- Phase 1: scores ----
    {
        const unsigned short* qp = QK + (size_t)(b * 256 + strip * 16 + r16) * 1024 + quad * 8;
        const unsigned short* kp0 = QK + (size_t)(b * 256 + w * 64 + r16) * 1024 + 512 + quad * 8;
        const unsigned short* kp1 = kp0 + 16 * 1024;
        const unsigned short* kp2 = kp0 + 32 * 1024;
        const unsigned short* kp3 = kp0 + 48 * 1024;

        f32x4 a0 = {0,0,0,0}, a1 = a0, a2 = a0, a3 = a0;
#pragma unroll 4
        for (int k = 0; k < 512; k += 32) {
            short8 qa = *(const short8*)(qp + k);
            short8 b0 = *(const short8*)(kp0 + k);
            short8 b1 = *(const short8*)(kp1 + k);
            short8 b2 = *(const short8*)(kp2 + k);
            short8 b3 = *(const short8*)(kp3 + k);
            a0 = mfma16(qa, b0, a0); a1 = mfma16(qa, b1, a1);
            a2 = mfma16(qa, b2, a2); a3 = mfma16(qa, b3, a3);
        }
        f32x4 accs[4] = {a0, a1, a2, a3};
#pragma unroll
        for (int j = 0; j < 4; ++j) {
            const int col = w * 64 + j * 16 + r16;
#pragma unroll
            for (int r = 0; r < 4; ++r)
                u.S[quad * 4 + r][col] = accs[j][r];
        }
    }
    __syncthreads();

    // ---- Phase 2: softmax -> bf16 A in LDS ----
    {
        const int t = threadIdx.x;
        const int r = t >> 4, idx = t & 15;     // row r, cols idx*16..+15
        float v[16];
        float mx = -3.4e38f;
#pragma unroll
        for (int j = 0; j < 16; ++j) {
            v[j] = u.S[r][idx * 16 + j] * 0.044194173824159216f;
            mx = fmaxf(mx, v[j]);
        }
        mx = fmaxf(mx, __shfl_xor(mx, 1));
        mx = fmaxf(mx, __shfl_xor(mx, 2));
        mx = fmaxf(mx, __shfl_xor(mx, 4));
        mx = fmaxf(mx, __shfl_xor(mx, 8));
        float sum = 0.f;
#pragma unroll
        for (int j = 0; j < 16; ++j) { v[j] = __expf(v[j] - mx); sum += v[j]; }
        sum += __shfl_xor(sum, 1);
        sum += __shfl_xor(sum, 2);
        sum += __shfl_xor(sum, 4);
        sum += __shfl_xor(sum, 8);
        const float inv = 1.f / sum;
        unsigned short* ap = &Abf[r][idx * 16];
#pragma unroll
        for (int j = 0; j < 16; j += 4)
            *(ushort4*)(ap + j) = make_ushort4(f2bf(v[j] * inv), f2bf(v[j + 1] * inv),
                                               f2bf(v[j + 2] * inv), f2bf(v[j + 3] * inv));
    }
    __syncthreads();

    // ---- Phase 3: AV for this c-half (per wave: 4 tiles of 16c x 16n) ----
    {
        f32x4 acc0 = {0,0,0,0}, acc1 = acc0, acc2 = acc0, acc3 = acc0;
        const unsigned short* vbase = VsT + (size_t)b * 131072 +
                                      (size_t)(chalf * 256 + w * 64 + r16) * 256 + quad * 8;
        const unsigned short* vp0 = vbase;
        const unsigned short* vp1 = vbase + 16 * 256;
        const unsigned short* vp2 = vbase + 32 * 256;
        const unsigned short* vp3 = vbase + 48 * 256;
#pragma unroll
        for (int kk = 0; kk < 256; kk += 32) {
            short8 a = *(const short8*)(&Abf[r16][kk + quad * 8]);
            short8 b0 = *(const short8*)(vp0 + kk);
            short8 b1 = *(const short8*)(vp1 + kk);
            short8 b2 = *(const short8*)(vp2 + kk);
            short8 b3 = *(const short8*)(vp3 + kk);
            acc0 = mfma16(a, b0, acc0); acc1 = mfma16(a, b1, acc1);
            acc2 = mfma16(a, b2, acc2); acc3 = mfma16(a, b3, acc3);
        }
        __syncthreads();                    // S dead; osT aliases it
        f32x4 accs[4] = {acc0, acc1, acc2, acc3};
#pragma unroll
        for (int i = 0; i < 4; ++i) {
            const int cl = w * 64 + i * 16 + r16;
#pragma unroll
            for (int r = 0; r < 4; ++r)
                u.osT[cl][quad * 4 + r] = accs[i][r];
        }
    }
    __syncthreads();

    // ---- Phase 4: expanded write, 1 KB contiguous per WAVE instruction ----
    {
        const int j = threadIdx.x & 63;     // float4 index within segment
        float* obase = out + (size_t)(b * 512 + chalf * 256) * 4096 + strip * 256 + j * 4;
#pragma unroll
        for (int it = 0; it < 64; ++it) {
            const int ch = it * 4 + w;
            const float v = u.osT[ch][j >> 2];
            *(float4*)(obase + (size_t)ch * 4096) = make_float4(v, v, v, v);
        }
    }
}

extern "C" void kernel_launch(void* const* d_in, const int* in_sizes, int n_in,
                              void* d_out, int out_size, void* d_ws, size_t ws_size,
                              hipStream_t stream) {
    const float* x  = (const float*)d_in[0];
    const float* Wq = (const float*)d_in[1];
    const float* bq = (const float*)d_in[2];
    const float* Wk = (const float*)d_in[3];
    const float* bk = (const float*)d_in[4];
    const float* Wv = (const float*)d_in[5];
    const float* bv = (const float*)d_in[6];
    float* out = (float*)d_out;

    // All scratch in d_ws; fully written before read each call.
    unsigned short* Wb   = (unsigned short*)d_ws;    // 786432 shorts (Wq|Wk|Wv)
    unsigned short* xavg = Wb + 786432;              // 1048576
    unsigned short* xsum = xavg + 1048576;           // 1048576
    unsigned short* QK   = xsum + 1048576;           // 2097152 (2048x1024)
    unsigned short* VsT  = QK + 2097152;             // 1048576 (8 x 512x256)

    // K1: coalesced-write plane reductions (512) + weight convert (384)
    prep_kernel<<<896, 256, 0, stream>>>(x, Wq, Wk, Wv, xavg, xsum, Wb);
    // K2: 32x16/wave, 1536 blocks, 8 waves/SIMD TLP experiment
    proj_gemm<<<1536, 256, 0, stream>>>(xavg, xsum, Wb, bq, bk, bv, QK, VsT);
    // K3: scores + softmax + AV + expanded write (256 blocks, champion config)
    score_av<<<dim3(32, 8), 256, 0, stream>>>(QK, VsT, out);
}

// Round 12
// 164.093 us; speedup vs baseline: 1.0658x; 1.0658x over previous
//
#include <hip/hip_runtime.h>

typedef __attribute__((ext_vector_type(8))) short short8;
typedef __attribute__((ext_vector_type(4))) float f32x4;

__device__ __forceinline__ unsigned short f2bf(float f) {
    union { float f; unsigned int i; } v; v.f = f;
    unsigned int x = v.i;
    return (unsigned short)((x + 0x7FFFu + ((x >> 16) & 1u)) >> 16); // RNE, finite inputs
}
__device__ __forceinline__ f32x4 mfma16(short8 a, short8 b, f32x4 c) {
    return __builtin_amdgcn_mfma_f32_16x16x32_bf16(a, b, c, 0, 0, 0);
}

// ---------------------------------------------------------------------------
// CHAMPION RESTORE (R7, 164.5 us). Session ledger: R8 +7.5 (4x score dup),
// R9 +0.9 (waves, null: throughput-bound), R10 +9.0 (un-merge: boundary
// ~5-9 us dominates), R11 +10.4 (K2 32x16: 1.5 loads/MFMA, L2-BW-bound).
// K1: coalesced-write input prep. Blocks 0..511: (b, 16ch group, half-plane),
// LDS transpose, 32 B-contiguous bf16 runs. Blocks 512..895: W -> bf16.
// ---------------------------------------------------------------------------
__global__ void __launch_bounds__(256, 4)
prep_kernel(const float* __restrict__ x,
            const float* __restrict__ Wq,
            const float* __restrict__ Wk,
            const float* __restrict__ Wv,
            unsigned short* __restrict__ xavg,
            unsigned short* __restrict__ xsum,
            unsigned short* __restrict__ Wb)
{
    const int blk = blockIdx.x;
    const int t = threadIdx.x;
    if (blk >= 512) {                       // weight conversion (unchanged math)
        const int f = (blk - 512) * 512 + t;    // float4 id; pair (f, f+256)
        const int m = f >> 16;                  // 65536 float4 per matrix
        const int o = f & 65535;
        const float4* s4 = (const float4*)((m == 0) ? Wq : (m == 1) ? Wk : Wv);
        float4 a = s4[o];
        float4 b = s4[o + 256];
        ushort4* d4 = (ushort4*)(Wb + (size_t)m * 262144);
        d4[o]       = make_ushort4(f2bf(a.x), f2bf(a.y), f2bf(a.z), f2bf(a.w));
        d4[o + 256] = make_ushort4(f2bf(b.x), f2bf(b.y), f2bf(b.z), f2bf(b.w));
        return;
    }

    const int b    = blk >> 6;              // 0..7
    const int rem  = blk & 63;
    const int cg   = rem >> 1;              // 0..31 : 16-channel group
    const int half = rem & 1;               // 0..1  : h-rows 0..31 / 32..63
    const int c0   = cg * 16;

    __shared__ float part[4][512];          // quad-sums for 4 channels
    __shared__ unsigned short xsT[16][128]; // [c_local][g_local]
    __shared__ unsigned short xaT[16][128]; // [c_local][n_local]

    for (int cg4 = 0; cg4 < 4; ++cg4) {     // 4 phases x 4 channels
        float4 a0, a1, b0, b1, c0v, c1, d0, d1;
        {
            const float* base = x + ((size_t)(b * 512 + c0 + cg4 * 4) * 4096) + half * 2048;
            const float4* p0 = (const float4*)(base);
            const float4* p1 = (const float4*)(base + 4096);
            const float4* p2 = (const float4*)(base + 8192);
            const float4* p3 = (const float4*)(base + 12288);
            a0 = p0[t]; a1 = p0[t + 256];
            b0 = p1[t]; b1 = p1[t + 256];
            c0v = p2[t]; c1 = p2[t + 256];
            d0 = p3[t]; d1 = p3[t + 256];
        }
        part[0][t]       = a0.x + a0.y + a0.z + a0.w;
        part[0][t + 256] = a1.x + a1.y + a1.z + a1.w;
        part[1][t]       = b0.x + b0.y + b0.z + b0.w;
        part[1][t + 256] = b1.x + b1.y + b1.z + b1.w;
        part[2][t]       = c0v.x + c0v.y + c0v.z + c0v.w;
        part[2][t + 256] = c1.x + c1.y + c1.z + c1.w;
        part[3][t]       = d0.x + d0.y + d0.z + d0.w;
        part[3][t + 256] = d1.x + d1.y + d1.z + d1.w;
        __syncthreads();

        if (t < 128) {                      // xsum: group g = 16 consecutive pixels
            const int g = t;
#pragma unroll
            for (int ci = 0; ci < 4; ++ci) {
                float4 q = *(const float4*)&part[ci][4 * g];
                xsT[cg4 * 4 + ci][g] = f2bf(q.x + q.y + q.z + q.w);
            }
        } else {                            // xavg: spatial block n = bh*16+bw (local)
            const int n = t - 128;
            const int bh = n >> 4, bw = n & 15;
#pragma unroll
            for (int ci = 0; ci < 4; ++ci) {
                float m = (part[ci][(bh * 4 + 0) * 16 + bw] + part[ci][(bh * 4 + 1) * 16 + bw] +
                           part[ci][(bh * 4 + 2) * 16 + bw] + part[ci][(bh * 4 + 3) * 16 + bw]) * 0.0625f;
                xaT[cg4 * 4 + ci][n] = f2bf(m);
            }
        }
        __syncthreads();                    // part reused next phase
    }

    {
        const int g = t >> 1, chunk = t & 1;    // row 0..127, 8-channel chunk
        const size_t rowbase = ((size_t)(b * 256) + half * 128 + g) * 512 + c0 + chunk * 8;
        short8 vs, va;
#pragma unroll
        for (int j = 0; j < 8; ++j) {
            vs[j] = (short)xsT[chunk * 8 + j][g];
            va[j] = (short)xaT[chunk * 8 + j][g];
        }
        *(short8*)(xsum + rowbase) = vs;
        *(short8*)(xavg + rowbase) = va;
    }
}

// ---------------------------------------------------------------------------
// K2: joint projection, 32x32 tile/wave (1.0 loads/MFMA), 768 blocks =
// 3 blocks/CU. Verified optimal: bigger tiles lose occupancy (R1: 32x64@384),
// smaller tiles raise L2 traffic 1.5x (R11: 32x16@1536, +10 us).
// ---------------------------------------------------------------------------
__global__ void __launch_bounds__(256, 3)
proj_gemm(const unsigned short* __restrict__ xavg,
          const unsigned short* __restrict__ xsum,
          const unsigned short* __restrict__ Wb,
          const float* __restrict__ bq,
          const float* __restrict__ bk,
          const float* __restrict__ bv,
          unsigned short* __restrict__ QK,
          unsigned short* __restrict__ VsT)
{
    const int blk = blockIdx.x;
    const int lane = threadIdx.x & 63, quad = lane >> 4, r16 = lane & 15;
    const int w = threadIdx.x >> 6;

    if (blk < 512) {                        // ---- QK projection ----
        const int wave = blk * 4 + w;       // 0..2047
        const int mt = wave >> 5;           // 0..63 (32-row tiles)
        const int nt = wave & 31;           // 0..31 (32-col tiles)
        const unsigned short* xp0 = xavg + (size_t)(mt * 32 + r16) * 512 + quad * 8;
        const unsigned short* xp1 = xp0 + 16 * 512;
        const unsigned short* wp0 = Wb + (size_t)(nt * 32 + r16) * 512 + quad * 8;
        const unsigned short* wp1 = wp0 + 16 * 512;

        f32x4 a00 = {0,0,0,0}, a01 = a00, a10 = a00, a11 = a00;
#pragma unroll 4
        for (int k = 0; k < 512; k += 32) {
            short8 qa0 = *(const short8*)(xp0 + k);
            short8 qa1 = *(const short8*)(xp1 + k);
            short8 b0 = *(const short8*)(wp0 + k);
            short8 b1 = *(const short8*)(wp1 + k);
            a00 = mfma16(qa0, b0, a00); a01 = mfma16(qa0, b1, a01);
            a10 = mfma16(qa1, b0, a10); a11 = mfma16(qa1, b1, a11);
        }
        const int row0 = mt * 32 + quad * 4;
        f32x4 accs0[2] = {a00, a01};
        f32x4 accs1[2] = {a10, a11};
#pragma unroll
        for (int j = 0; j < 2; ++j) {
            const int c = nt * 32 + j * 16 + r16;
            const float bias = (c < 512) ? bq[c] : bk[c - 512];
#pragma unroll
            for (int r = 0; r < 4; ++r) {
                QK[(size_t)(row0 + r) * 1024 + c]      = f2bf(accs0[j][r] + bias);
                QK[(size_t)(row0 + 16 + r) * 1024 + c] = f2bf(accs1[j][r] + bias);
            }
        }
    } else {                                // ---- V projection (transposed) ----
        const int vblk = blk - 512;         // 0..255
        const int b = vblk >> 5;            // 0..7
        const int wib = (vblk & 31) * 4 + w;    // 0..127
        const int mt2 = wib >> 4;           // 0..7 (32-row tiles of 256)
        const int nt = wib & 15;            // 0..15 (32-col tiles of 512)
        const unsigned short* xp0 = xsum + (size_t)b * 131072 + (size_t)(mt2 * 32 + r16) * 512 + quad * 8;
        const unsigned short* xp1 = xp0 + 16 * 512;
        const unsigned short* wp0 = Wb + 524288 + (size_t)(nt * 32 + r16) * 512 + quad * 8;
        const unsigned short* wp1 = wp0 + 16 * 512;

        f32x4 a00 = {0,0,0,0}, a01 = a00, a10 = a00, a11 = a00;
#pragma unroll 4
        for (int k = 0; k < 512; k += 32) {
            short8 qa0 = *(const short8*)(xp0 + k);
            short8 qa1 = *(const short8*)(xp1 + k);
            short8 b0 = *(const short8*)(wp0 + k);
            short8 b1 = *(const short8*)(wp1 + k);
            a00 = mfma16(qa0, b0, a00); a01 = mfma16(qa0, b1, a01);
            a10 = mfma16(qa1, b0, a10); a11 = mfma16(qa1, b1, a11);
        }
        unsigned short* vb = VsT + (size_t)b * 131072;
        const int m0 = mt2 * 32 + quad * 4;
        f32x4 accs0[2] = {a00, a01};
        f32x4 accs1[2] = {a10, a11};
#pragma unroll
        for (int j = 0; j < 2; ++j) {
            const int c = nt * 32 + j * 16 + r16;
            const float bias = 16.f * bv[c];
#pragma unroll
            for (int r = 0; r < 4; ++r) {
                vb[(size_t)c * 256 + m0 + r]      = f2bf(accs0[j][r] + bias);
                vb[(size_t)c * 256 + m0 + 16 + r] = f2bf(accs1[j][r] + bias);
            }
        }
    }
}

// ---------------------------------------------------------------------------
// K3: scores + softmax + AV + expand, merged. 256 blocks (1/CU), 2x score
// duplication, wave-coalesced 1 KB/instr expanded writes. Verified optimal:
// 4x dup +7.5 (R8), 8-wave null (R9), un-merged +9 (R10).
// ---------------------------------------------------------------------------
__global__ void __launch_bounds__(256, 2)
score_av(const unsigned short* __restrict__ QK,
         const unsigned short* __restrict__ VsT,
         float* __restrict__ out)
{
    __shared__ union {
        float S[16][257];
        float osT[256][17];
    } u;
    __shared__ __align__(16) unsigned short Abf[16][264];   // +8 pad: row stride 528 B

    const int b = blockIdx.y;
    const int strip = blockIdx.x >> 1;      // 0..15
    const int chalf = blockIdx.x & 1;       // 0..1: which 256-channel half
    const int w = threadIdx.x >> 6, lane = threadIdx.x & 63;
    const int quad = lane >> 4, r16 = lane & 15;

    // ---- Phase 1: scores ----
    {
        const unsigned short* qp = QK + (size_t)(b * 256 + strip * 16 + r16) * 1024 + quad * 8;
        const unsigned short* kp0 = QK + (size_t)(b * 256 + w * 64 + r16) * 1024 + 512 + quad * 8;
        const unsigned short* kp1 = kp0 + 16 * 1024;
        const unsigned short* kp2 = kp0 + 32 * 1024;
        const unsigned short* kp3 = kp0 + 48 * 1024;

        f32x4 a0 = {0,0,0,0}, a1 = a0, a2 = a0, a3 = a0;
#pragma unroll 4
        for (int k = 0; k < 512; k += 32) {
            short8 qa = *(const short8*)(qp + k);
            short8 b0 = *(const short8*)(kp0 + k);
            short8 b1 = *(const short8*)(kp1 + k);
            short8 b2 = *(const short8*)(kp2 + k);
            short8 b3 = *(const short8*)(kp3 + k);
            a0 = mfma16(qa, b0, a0); a1 = mfma16(qa, b1, a1);
            a2 = mfma16(qa, b2, a2); a3 = mfma16(qa, b3, a3);
        }
        f32x4 accs[4] = {a0, a1, a2, a3};
#pragma unroll
        for (int j = 0; j < 4; ++j) {
            const int col = w * 64 + j * 16 + r16;
#pragma unroll
            for (int r = 0; r < 4; ++r)
                u.S[quad * 4 + r][col] = accs[j][r];
        }
    }
    __syncthreads();

    // ---- Phase 2: softmax -> bf16 A in LDS ----
    {
        const int t = threadIdx.x;
        const int r = t >> 4, idx = t & 15;     // row r, cols idx*16..+15
        float v[16];
        float mx = -3.4e38f;
#pragma unroll
        for (int j = 0; j < 16; ++j) {
            v[j] = u.S[r][idx * 16 + j] * 0.044194173824159216f;
            mx = fmaxf(mx, v[j]);
        }
        mx = fmaxf(mx, __shfl_xor(mx, 1));
        mx = fmaxf(mx, __shfl_xor(mx, 2));
        mx = fmaxf(mx, __shfl_xor(mx, 4));
        mx = fmaxf(mx, __shfl_xor(mx, 8));
        float sum = 0.f;
#pragma unroll
        for (int j = 0; j < 16; ++j) { v[j] = __expf(v[j] - mx); sum += v[j]; }
        sum += __shfl_xor(sum, 1);
        sum += __shfl_xor(sum, 2);
        sum += __shfl_xor(sum, 4);
        sum += __shfl_xor(sum, 8);
        const float inv = 1.f / sum;
        unsigned short* ap = &Abf[r][idx * 16];
#pragma unroll
        for (int j = 0; j < 16; j += 4)
            *(ushort4*)(ap + j) = make_ushort4(f2bf(v[j] * inv), f2bf(v[j + 1] * inv),
                                               f2bf(v[j + 2] * inv), f2bf(v[j + 3] * inv));
    }
    __syncthreads();

    // ---- Phase 3: AV for this c-half (per wave: 4 tiles of 16c x 16n) ----
    {
        f32x4 acc0 = {0,0,0,0}, acc1 = acc0, acc2 = acc0, acc3 = acc0;
        const unsigned short* vbase = VsT + (size_t)b * 131072 +
                                      (size_t)(chalf * 256 + w * 64 + r16) * 256 + quad * 8;
        const unsigned short* vp0 = vbase;
        const unsigned short* vp1 = vbase + 16 * 256;
        const unsigned short* vp2 = vbase + 32 * 256;
        const unsigned short* vp3 = vbase + 48 * 256;
#pragma unroll
        for (int kk = 0; kk < 256; kk += 32) {
            short8 a = *(const short8*)(&Abf[r16][kk + quad * 8]);
            short8 b0 = *(const short8*)(vp0 + kk);
            short8 b1 = *(const short8*)(vp1 + kk);
            short8 b2 = *(const short8*)(vp2 + kk);
            short8 b3 = *(const short8*)(vp3 + kk);
            acc0 = mfma16(a, b0, acc0); acc1 = mfma16(a, b1, acc1);
            acc2 = mfma16(a, b2, acc2); acc3 = mfma16(a, b3, acc3);
        }
        __syncthreads();                    // S dead; osT aliases it
        f32x4 accs[4] = {acc0, acc1, acc2, acc3};
#pragma unroll
        for (int i = 0; i < 4; ++i) {
            const int cl = w * 64 + i * 16 + r16;
#pragma unroll
            for (int r = 0; r < 4; ++r)
                u.osT[cl][quad * 4 + r] = accs[i][r];
        }
    }
    __syncthreads();

    // ---- Phase 4: expanded write, 1 KB contiguous per WAVE instruction ----
    {
        const int j = threadIdx.x & 63;     // float4 index within segment
        float* obase = out + (size_t)(b * 512 + chalf * 256) * 4096 + strip * 256 + j * 4;
#pragma unroll
        for (int it = 0; it < 64; ++it) {
            const int ch = it * 4 + w;
            const float v = u.osT[ch][j >> 2];
            *(float4*)(obase + (size_t)ch * 4096) = make_float4(v, v, v, v);
        }
    }
}

extern "C" void kernel_launch(void* const* d_in, const int* in_sizes, int n_in,
                              void* d_out, int out_size, void* d_ws, size_t ws_size,
                              hipStream_t stream) {
    const float* x  = (const float*)d_in[0];
    const float* Wq = (const float*)d_in[1];
    const float* bq = (const float*)d_in[2];
    const float* Wk = (const float*)d_in[3];
    const float* bk = (const float*)d_in[4];
    const float* Wv = (const float*)d_in[5];
    const float* bv = (const float*)d_in[6];
    float* out = (float*)d_out;

    // All scratch in d_ws; fully written before read each call.
    unsigned short* Wb   = (unsigned short*)d_ws;    // 786432 shorts (Wq|Wk|Wv)
    unsigned short* xavg = Wb + 786432;              // 1048576
    unsigned short* xsum = xavg + 1048576;           // 1048576
    unsigned short* QK   = xsum + 1048576;           // 2097152 (2048x1024)
    unsigned short* VsT  = QK + 2097152;             // 1048576 (8 x 512x256)

    // K1: coalesced-write plane reductions (512) + weight convert (384)
    prep_kernel<<<896, 256, 0, stream>>>(x, Wq, Wk, Wv, xavg, xsum, Wb);
    // K2: QK = xavg @ [Wq;Wk]^T + bias  AND  VsT = (xsum @ Wv^T + 16*bv)^T
    proj_gemm<<<768, 256, 0, stream>>>(xavg, xsum, Wb, bq, bk, bv, QK, VsT);
    // K3: scores + softmax + AV + expanded write (256 blocks, champion config)
    score_av<<<dim3(32, 8), 256, 0, stream>>>(QK, VsT, out);
}